// Round 1
// baseline (1829.108 us; speedup 1.0000x reference)
//
#include <hip/hip_runtime.h>

// TPF encoder: 2 tree levels; per level:
//   edge:  bh = relu(LN(relu(LN([h[src],bond] @ W1 + b1)) @ W2 + b2)); agg[dst] += bh
//   node:  f  = relu(LN([ax,agg] @ sW1 + sb1));  f = relu(LN(f @ sW2 + sb2));
//          h  = relu(LN([ax,f] @ hW + hb))
// All dims 128 (TREE=BASIC=128), concat inputs are 256-wide.
//
// Baseline design (fp32, correctness-first):
//  - 32 rows/block, 256 threads, 4x4 register tile per thread (rows (t>>5)*4.., cols (t&31)*4..)
//  - input tile staged in LDS as [32][256] (float4-readable); inner loop: 4 ds_read_b128
//    + 4 global float4 W loads -> 64 FMA  (compute-bound, not LDS-issue-bound)
//  - LN: pre-LN tile to LDS scratch stride 129 (conflict-free row reduce by 32 threads)
//  - segment_sum via fp32 atomicAdd (device scope), agg zeroed with hipMemsetAsync

#define D    128
#define TE   32
#define SSTR 129   // LDS scratch stride (129%32 != 0 -> conflict-free row reduce)

__device__ __forceinline__ void gemm_tile(const float4* __restrict__ in4, int kcN,
                                          const float* __restrict__ W,
                                          const float* __restrict__ b,
                                          int rgrp, int c0, float acc[4][4])
{
    float4 bv = *(const float4*)(b + c0);
#pragma unroll
    for (int r = 0; r < 4; ++r) {
        acc[r][0] = bv.x; acc[r][1] = bv.y; acc[r][2] = bv.z; acc[r][3] = bv.w;
    }
    for (int kc = 0; kc < kcN; ++kc) {
        float4 w0 = *(const float4*)(W + (size_t)(kc * 4 + 0) * D + c0);
        float4 w1 = *(const float4*)(W + (size_t)(kc * 4 + 1) * D + c0);
        float4 w2 = *(const float4*)(W + (size_t)(kc * 4 + 2) * D + c0);
        float4 w3 = *(const float4*)(W + (size_t)(kc * 4 + 3) * D + c0);
#pragma unroll
        for (int r = 0; r < 4; ++r) {
            float4 x = in4[(rgrp + r) * kcN + kc];
            acc[r][0] = fmaf(x.x, w0.x, fmaf(x.y, w1.x, fmaf(x.z, w2.x, fmaf(x.w, w3.x, acc[r][0]))));
            acc[r][1] = fmaf(x.x, w0.y, fmaf(x.y, w1.y, fmaf(x.z, w2.y, fmaf(x.w, w3.y, acc[r][1]))));
            acc[r][2] = fmaf(x.x, w0.z, fmaf(x.y, w1.z, fmaf(x.z, w2.z, fmaf(x.w, w3.z, acc[r][2]))));
            acc[r][3] = fmaf(x.x, w0.w, fmaf(x.y, w1.w, fmaf(x.z, w2.w, fmaf(x.w, w3.w, acc[r][3]))));
        }
    }
}

// LayerNorm(axis=-1 over 128) + relu, in-place on acc. Uses scratch[TE*SSTR], ms[TE*2].
__device__ __forceinline__ void ln_relu(float acc[4][4], float* scratch, float* ms,
                                        const float* __restrict__ g,
                                        const float* __restrict__ be,
                                        int rgrp, int c0, int t)
{
#pragma unroll
    for (int r = 0; r < 4; ++r)
#pragma unroll
        for (int c = 0; c < 4; ++c)
            scratch[(rgrp + r) * SSTR + c0 + c] = acc[r][c];
    __syncthreads();
    if (t < TE) {
        float s = 0.f, ss = 0.f;
        for (int k = 0; k < D; ++k) {
            float v = scratch[t * SSTR + k];
            s += v; ss += v * v;
        }
        float m   = s * (1.f / D);
        float var = ss * (1.f / D) - m * m;
        ms[t * 2 + 0] = m;
        ms[t * 2 + 1] = rsqrtf(var + 1e-5f);
    }
    __syncthreads();
    float4 gv  = *(const float4*)(g + c0);
    float4 bev = *(const float4*)(be + c0);
#pragma unroll
    for (int r = 0; r < 4; ++r) {
        float m  = ms[(rgrp + r) * 2 + 0];
        float rs = ms[(rgrp + r) * 2 + 1];
        acc[r][0] = fmaxf((acc[r][0] - m) * rs * gv.x + bev.x, 0.f);
        acc[r][1] = fmaxf((acc[r][1] - m) * rs * gv.y + bev.y, 0.f);
        acc[r][2] = fmaxf((acc[r][2] - m) * rs * gv.z + bev.z, 0.f);
        acc[r][3] = fmaxf((acc[r][3] - m) * rs * gv.w + bev.w, 0.f);
    }
}

__global__ __launch_bounds__(256) void edge_mlp(
    const float* __restrict__ hsrc, const float* __restrict__ bond,
    const int* __restrict__ src, const int* __restrict__ dst,
    const float* __restrict__ W1, const float* __restrict__ b1,
    const float* __restrict__ g1, const float* __restrict__ be1,
    const float* __restrict__ W2, const float* __restrict__ b2,
    const float* __restrict__ g2, const float* __restrict__ be2,
    float* __restrict__ agg, int E)
{
    __shared__ float s_ex[TE * 256];      // input tile [32][256]
    __shared__ float s_buf[TE * SSTR];    // LN scratch / normalized (aliased)
    __shared__ float s_ms[TE * 2];
    __shared__ int   s_src[TE];
    __shared__ int   s_dst[TE];

    int t  = threadIdx.x;
    int eb = blockIdx.x * TE;

    if (t < TE) {
        int ge = eb + t;
        s_src[t] = (ge < E) ? src[ge] : 0;
        s_dst[t] = (ge < E) ? dst[ge] : -1;
    }
    __syncthreads();

    {   // stage ex = [h[src] | bond]
        const float4* h4 = (const float4*)hsrc;
        const float4* b4 = (const float4*)bond;
        float4* ex4 = (float4*)s_ex;
        for (int c = t; c < TE * 64; c += 256) {
            int e = c >> 6, k4 = c & 63;
            int ge = eb + e;
            float4 v = make_float4(0.f, 0.f, 0.f, 0.f);
            if (ge < E) {
                if (k4 < 32) v = h4[(size_t)s_src[e] * 32 + k4];
                else         v = b4[(size_t)ge * 32 + (k4 - 32)];
            }
            ex4[c] = v;
        }
    }
    __syncthreads();

    int c0   = (t & 31) * 4;
    int rgrp = (t >> 5) * 4;
    float acc[4][4];

    // layer 1: 256 -> 128
    gemm_tile((const float4*)s_ex, 64, W1, b1, rgrp, c0, acc);
    ln_relu(acc, s_buf, s_ms, g1, be1, rgrp, c0, t);

    // normalized -> compact [32][128] in s_buf (safe: scratch reads done at ln barrier)
    {
        float4* n4 = (float4*)s_buf;
#pragma unroll
        for (int r = 0; r < 4; ++r)
            n4[(rgrp + r) * 32 + (t & 31)] =
                make_float4(acc[r][0], acc[r][1], acc[r][2], acc[r][3]);
    }
    __syncthreads();

    // layer 2: 128 -> 128
    gemm_tile((const float4*)s_buf, 32, W2, b2, rgrp, c0, acc);
    __syncthreads();  // all reads of s_buf done before ln scratch overwrites it
    ln_relu(acc, s_buf, s_ms, g2, be2, rgrp, c0, t);

    // scatter-add to agg[dst]
#pragma unroll
    for (int r = 0; r < 4; ++r) {
        int gd = s_dst[rgrp + r];
        if (gd >= 0) {
            float* p = agg + (size_t)gd * D + c0;
            atomicAdd(p + 0, acc[r][0]);
            atomicAdd(p + 1, acc[r][1]);
            atomicAdd(p + 2, acc[r][2]);
            atomicAdd(p + 3, acc[r][3]);
        }
    }
}

__global__ __launch_bounds__(256) void node_mlp(
    const float* __restrict__ ax, const float* __restrict__ agg,
    const float* __restrict__ W1, const float* __restrict__ b1,
    const float* __restrict__ g1, const float* __restrict__ be1,
    const float* __restrict__ W2, const float* __restrict__ b2,
    const float* __restrict__ g2, const float* __restrict__ be2,
    const float* __restrict__ Wh, const float* __restrict__ bh,
    const float* __restrict__ gh, const float* __restrict__ beh,
    float* __restrict__ out, int N)
{
    __shared__ float s_ex[TE * 256];
    __shared__ float s_buf[TE * SSTR];
    __shared__ float s_ms[TE * 2];

    int t  = threadIdx.x;
    int rb = blockIdx.x * TE;

    {   // stage sx = [ax | agg]
        const float4* a4 = (const float4*)ax;
        const float4* g4 = (const float4*)agg;
        float4* ex4 = (float4*)s_ex;
        for (int c = t; c < TE * 64; c += 256) {
            int e = c >> 6, k4 = c & 63;
            int gr = rb + e;
            float4 v = make_float4(0.f, 0.f, 0.f, 0.f);
            if (gr < N) {
                if (k4 < 32) v = a4[(size_t)gr * 32 + k4];
                else         v = g4[(size_t)gr * 32 + (k4 - 32)];
            }
            ex4[c] = v;
        }
    }
    __syncthreads();

    int c0   = (t & 31) * 4;
    int rgrp = (t >> 5) * 4;
    float acc[4][4];

    // sub layer 1: 256 -> 128
    gemm_tile((const float4*)s_ex, 64, W1, b1, rgrp, c0, acc);
    ln_relu(acc, s_buf, s_ms, g1, be1, rgrp, c0, t);
    {
        float4* n4 = (float4*)s_buf;
#pragma unroll
        for (int r = 0; r < 4; ++r)
            n4[(rgrp + r) * 32 + (t & 31)] =
                make_float4(acc[r][0], acc[r][1], acc[r][2], acc[r][3]);
    }
    __syncthreads();

    // sub layer 2: 128 -> 128
    gemm_tile((const float4*)s_buf, 32, W2, b2, rgrp, c0, acc);
    __syncthreads();
    ln_relu(acc, s_buf, s_ms, g2, be2, rgrp, c0, t);

    // f2 into second half of s_ex -> th = [ax | f2]
    {
        float4* ex4 = (float4*)s_ex;
#pragma unroll
        for (int r = 0; r < 4; ++r)
            ex4[(rgrp + r) * 64 + 32 + (t & 31)] =
                make_float4(acc[r][0], acc[r][1], acc[r][2], acc[r][3]);
    }
    __syncthreads();

    // head layer: 256 -> 128
    gemm_tile((const float4*)s_ex, 64, Wh, bh, rgrp, c0, acc);
    ln_relu(acc, s_buf, s_ms, gh, beh, rgrp, c0, t);

    float4* o4 = (float4*)out;
#pragma unroll
    for (int r = 0; r < 4; ++r) {
        int gr = rb + rgrp + r;
        if (gr < N)
            o4[(size_t)gr * 32 + (t & 31)] =
                make_float4(acc[r][0], acc[r][1], acc[r][2], acc[r][3]);
    }
}

extern "C" void kernel_launch(void* const* d_in, const int* in_sizes, int n_in,
                              void* d_out, int out_size, void* d_ws, size_t ws_size,
                              hipStream_t stream)
{
    const float* h2   = (const float*)d_in[0];
    const float* ax1  = (const float*)d_in[1];
    const float* ax0  = (const float*)d_in[2];
    const float* bx2  = (const float*)d_in[3];
    const float* bx1  = (const float*)d_in[4];
    const float* brW1 = (const float*)d_in[5];
    const float* brb1 = (const float*)d_in[6];
    const float* brg1 = (const float*)d_in[7];
    const float* brbe1= (const float*)d_in[8];
    const float* brW2 = (const float*)d_in[9];
    const float* brb2 = (const float*)d_in[10];
    const float* brg2 = (const float*)d_in[11];
    const float* brbe2= (const float*)d_in[12];
    const float* sW1  = (const float*)d_in[13];
    const float* sb1  = (const float*)d_in[14];
    const float* sg1  = (const float*)d_in[15];
    const float* sbe1 = (const float*)d_in[16];
    const float* sW2  = (const float*)d_in[17];
    const float* sb2  = (const float*)d_in[18];
    const float* sg2  = (const float*)d_in[19];
    const float* sbe2 = (const float*)d_in[20];
    const float* hW   = (const float*)d_in[21];
    const float* hb   = (const float*)d_in[22];
    const float* hg   = (const float*)d_in[23];
    const float* hbe  = (const float*)d_in[24];
    const int*   src2 = (const int*)d_in[25];
    const int*   dst2 = (const int*)d_in[26];
    const int*   src1 = (const int*)d_in[27];
    const int*   dst1 = (const int*)d_in[28];

    int n2 = in_sizes[0] / D;
    int n1 = in_sizes[1] / D;
    int n0 = in_sizes[2] / D;

    float* agg = (float*)d_ws;                 // [n1][128] (reused as [n0][128])
    float* h1  = agg + (size_t)n1 * D;         // [n1][128]

    const int W1s = 256 * D;   // per-level stride of [2,256,128] weights
    const int W2s = D * D;     // per-level stride of [2,128,128] weights

    // ---- iteration 0 (level 2 -> level 1) ----
    hipMemsetAsync(agg, 0, (size_t)n1 * D * sizeof(float), stream);
    edge_mlp<<<dim3((n2 + TE - 1) / TE), dim3(256), 0, stream>>>(
        h2, bx2, src2, dst2,
        brW1, brb1, brg1, brbe1, brW2, brb2, brg2, brbe2, agg, n2);
    node_mlp<<<dim3((n1 + TE - 1) / TE), dim3(256), 0, stream>>>(
        ax1, agg,
        sW1, sb1, sg1, sbe1, sW2, sb2, sg2, sbe2, hW, hb, hg, hbe, h1, n1);

    // ---- iteration 1 (level 1 -> level 0) ----
    hipMemsetAsync(agg, 0, (size_t)n0 * D * sizeof(float), stream);
    edge_mlp<<<dim3((n1 + TE - 1) / TE), dim3(256), 0, stream>>>(
        h1, bx1, src1, dst1,
        brW1 + W1s, brb1 + D, brg1 + D, brbe1 + D,
        brW2 + W2s, brb2 + D, brg2 + D, brbe2 + D, agg, n1);
    node_mlp<<<dim3((n0 + TE - 1) / TE), dim3(256), 0, stream>>>(
        ax0, agg,
        sW1 + W1s, sb1 + D, sg1 + D, sbe1 + D,
        sW2 + W2s, sb2 + D, sg2 + D, sbe2 + D,
        hW + W1s, hb + D, hg + D, hbe + D, (float*)d_out, n0);
}

// Round 2
// 709.593 us; speedup vs baseline: 2.5777x; 2.5777x over previous
//
#include <hip/hip_runtime.h>

// TPF encoder, MFMA fp16 version.
// Per level: edge MLP (256->128, 128->128, both LN+relu) -> atomic segment-sum ->
// node MLP (256->128, 128->128, head 256->128, all LN+relu).
//
// - Weights packed per launch to Wp[kb][n][kk] fp16 (kk = 32 k-values contiguous):
//   B-fragment of mfma_f32_16x16x32 is one 16B load/lane, wave reads 1KB contiguous.
// - Activations staged in LDS fp16, row stride 264 (264*2B=528B = 132 dwords, 132%32=4
//   -> bank-balanced ds_read_b128 A-frags and staging writes).
// - LayerNorm in-register from MFMA C/D layout: per-lane partials over 4 col-tiles,
//   shuffle-xor over the 16-lane n-group, tiny LDS combine across the 2 col-half waves.
// - Block = 32 rows, 256 threads = 4 waves; wave w: rows 16*(w&1), cols 64*(w>>1),
//   per wave 4 16x16 tiles (acc = 4x f32x4).
// - h1 intermediate kept in fp16 (halves iter-1 gather traffic). agg fp32 + atomicAdd.

#define D   128
#define TE  32
#define XS  264   // s_x row stride in fp16 elems
#define YS  136   // s_y row stride

typedef float  f32x4 __attribute__((ext_vector_type(4)));
typedef _Float16 f16x8 __attribute__((ext_vector_type(8)));

__device__ __forceinline__ unsigned short f2h(float f) {
    union { _Float16 h; unsigned short u; } x;
    x.h = (_Float16)f;
    return x.u;
}

// ---- weight pack: Wp[kb*4096 + n*32 + kk] = fp16(W[kb*32+kk][n]) per matrix,level ----
__global__ __launch_bounds__(256) void pack_w(
    const float* __restrict__ brW1, const float* __restrict__ brW2,
    const float* __restrict__ sW1,  const float* __restrict__ sW2,
    const float* __restrict__ hW,   unsigned short* __restrict__ Wp)
{
    int p = blockIdx.x * 256 + threadIdx.x;   // 0 .. 262143
    const float* src; int off, K;
    if (p < 65536)       { src = brW1; off = 0;      K = 256; }
    else if (p < 98304)  { src = brW2; off = 65536;  K = 128; }
    else if (p < 163840) { src = sW1;  off = 98304;  K = 256; }
    else if (p < 196608) { src = sW2;  off = 163840; K = 128; }
    else                 { src = hW;   off = 196608; K = 256; }
    int q = p - off, lvl, r;
    if (K == 256) { lvl = q >> 15; r = q & 32767; }
    else          { lvl = q >> 14; r = q & 16383; }
    int kb = r >> 12, n = (r >> 5) & 127, kk = r & 31;
    Wp[p] = f2h(src[(size_t)lvl * K * 128 + (size_t)(kb * 32 + kk) * 128 + n]);
}

template<int KB>
__device__ __forceinline__ void gemm_f16(const unsigned short* s_in, int stride,
    const unsigned short* __restrict__ Wp, int rb, int cb, int n15, int q, f32x4 acc[4])
{
    f32x4 zero = {0.f, 0.f, 0.f, 0.f};
#pragma unroll
    for (int ct = 0; ct < 4; ++ct) acc[ct] = zero;
#pragma unroll
    for (int kb = 0; kb < KB; ++kb) {
        f16x8 af = *(const f16x8*)(s_in + (rb + n15) * stride + kb * 32 + q * 8);
        const unsigned short* wb = Wp + (size_t)kb * 4096 + q * 8;
#pragma unroll
        for (int ct = 0; ct < 4; ++ct) {
            f16x8 bf = *(const f16x8*)(wb + (cb + ct * 16 + n15) * 32);
            acc[ct] = __builtin_amdgcn_mfma_f32_16x16x32_f16(af, bf, acc[ct], 0, 0, 0);
        }
    }
}

// bias + LayerNorm + relu, in-place on acc (MFMA C layout: row=rb+q*4+r, col=cb+ct*16+n15)
__device__ __forceinline__ void ln_relu(f32x4 acc[4],
    const float* __restrict__ b, const float* __restrict__ g, const float* __restrict__ be,
    float* s_red, float* s_ms, int rb, int cb, int n15, int q, int wcol, int t)
{
#pragma unroll
    for (int ct = 0; ct < 4; ++ct) {
        float bb = b[cb + ct * 16 + n15];
#pragma unroll
        for (int r = 0; r < 4; ++r) acc[ct][r] += bb;
    }
    float sum[4], ss[4];
#pragma unroll
    for (int r = 0; r < 4; ++r) {
        sum[r] = acc[0][r] + acc[1][r] + acc[2][r] + acc[3][r];
        ss[r]  = acc[0][r]*acc[0][r] + acc[1][r]*acc[1][r]
               + acc[2][r]*acc[2][r] + acc[3][r]*acc[3][r];
    }
#pragma unroll
    for (int off = 1; off < 16; off <<= 1) {
#pragma unroll
        for (int r = 0; r < 4; ++r) {
            sum[r] += __shfl_xor(sum[r], off, 64);
            ss[r]  += __shfl_xor(ss[r],  off, 64);
        }
    }
    if (n15 == 0) {
#pragma unroll
        for (int r = 0; r < 4; ++r) {
            int row = rb + q * 4 + r;
            s_red[row * 4 + wcol * 2 + 0] = sum[r];
            s_red[row * 4 + wcol * 2 + 1] = ss[r];
        }
    }
    __syncthreads();
    if (t < TE) {
        float sm = s_red[t * 4 + 0] + s_red[t * 4 + 2];
        float sq = s_red[t * 4 + 1] + s_red[t * 4 + 3];
        float mean = sm * (1.f / 128.f);
        float var  = sq * (1.f / 128.f) - mean * mean;
        s_ms[t * 2 + 0] = mean;
        s_ms[t * 2 + 1] = rsqrtf(var + 1e-5f);
    }
    __syncthreads();
#pragma unroll
    for (int ct = 0; ct < 4; ++ct) {
        float gg = g[cb + ct * 16 + n15], bb = be[cb + ct * 16 + n15];
#pragma unroll
        for (int r = 0; r < 4; ++r) {
            int row = rb + q * 4 + r;
            float v = (acc[ct][r] - s_ms[row * 2 + 0]) * s_ms[row * 2 + 1] * gg + bb;
            acc[ct][r] = fmaxf(v, 0.f);
        }
    }
}

template<bool HBF16>
__global__ __launch_bounds__(256, 4) void edge_mlp(
    const void* __restrict__ hsrc, const float* __restrict__ bond,
    const int* __restrict__ src, const int* __restrict__ dst,
    const unsigned short* __restrict__ Wp1, const unsigned short* __restrict__ Wp2,
    const float* __restrict__ b1, const float* __restrict__ g1, const float* __restrict__ be1,
    const float* __restrict__ b2, const float* __restrict__ g2, const float* __restrict__ be2,
    float* __restrict__ agg, int E)
{
    __shared__ unsigned short s_x[TE * XS];
    __shared__ unsigned short s_y[TE * YS];
    __shared__ float s_red[TE * 4];
    __shared__ float s_ms[TE * 2];
    __shared__ int s_src[TE], s_dst[TE];

    int t = threadIdx.x, eb = blockIdx.x * TE;
    if (t < TE) {
        int ge = eb + t;
        s_src[t] = (ge < E) ? src[ge] : -1;
        s_dst[t] = (ge < E) ? dst[ge] : -1;
    }
    __syncthreads();

    if (HBF16) {   // h is fp16 (our h1 intermediate)
        const unsigned short* hp = (const unsigned short*)hsrc;
        for (int c = t; c < TE * 16; c += 256) {
            int row = c >> 4, k8 = c & 15;
            int s = s_src[row];
            uint4 v = make_uint4(0, 0, 0, 0);
            if (s >= 0) v = *(const uint4*)(hp + (size_t)s * 128 + k8 * 8);
            *(uint4*)(s_x + row * XS + k8 * 8) = v;
        }
    } else {       // h is fp32 (input subtree_h_top)
        const float* hp = (const float*)hsrc;
        for (int c = t; c < TE * 32; c += 256) {
            int row = c >> 5, k4 = c & 31;
            int s = s_src[row];
            float4 v = make_float4(0, 0, 0, 0);
            if (s >= 0) v = *(const float4*)(hp + (size_t)s * 128 + k4 * 4);
            ushort4 o; o.x = f2h(v.x); o.y = f2h(v.y); o.z = f2h(v.z); o.w = f2h(v.w);
            *(ushort4*)(s_x + row * XS + k4 * 4) = o;
        }
    }
    for (int c = t; c < TE * 32; c += 256) {   // bond part (always fp32)
        int row = c >> 5, k4 = c & 31;
        int ge = eb + row;
        float4 v = make_float4(0, 0, 0, 0);
        if (ge < E) v = *(const float4*)(bond + (size_t)ge * 128 + k4 * 4);
        ushort4 o; o.x = f2h(v.x); o.y = f2h(v.y); o.z = f2h(v.z); o.w = f2h(v.w);
        *(ushort4*)(s_x + row * XS + 128 + k4 * 4) = o;
    }
    __syncthreads();

    int l = t & 63, w = t >> 6;
    int n15 = l & 15, q = l >> 4;
    int rb = (w & 1) * 16, cb = (w >> 1) * 64, wcol = w >> 1;

    f32x4 acc[4];
    gemm_f16<8>(s_x, XS, Wp1, rb, cb, n15, q, acc);
    ln_relu(acc, b1, g1, be1, s_red, s_ms, rb, cb, n15, q, wcol, t);
#pragma unroll
    for (int ct = 0; ct < 4; ++ct)
#pragma unroll
        for (int r = 0; r < 4; ++r)
            s_y[(rb + q * 4 + r) * YS + cb + ct * 16 + n15] = f2h(acc[ct][r]);
    __syncthreads();
    gemm_f16<4>(s_y, YS, Wp2, rb, cb, n15, q, acc);
    ln_relu(acc, b2, g2, be2, s_red, s_ms, rb, cb, n15, q, wcol, t);

#pragma unroll
    for (int ct = 0; ct < 4; ++ct)
#pragma unroll
        for (int r = 0; r < 4; ++r) {
            int row = rb + q * 4 + r;
            int gd = s_dst[row];
            if (gd >= 0)
                atomicAdd(agg + (size_t)gd * D + cb + ct * 16 + n15, acc[ct][r]);
        }
}

template<bool OUT_F16>
__global__ __launch_bounds__(256, 4) void node_mlp(
    const float* __restrict__ ax, const float* __restrict__ agg,
    const unsigned short* __restrict__ Wp1, const unsigned short* __restrict__ Wp2,
    const unsigned short* __restrict__ Wp3,
    const float* __restrict__ b1, const float* __restrict__ g1, const float* __restrict__ be1,
    const float* __restrict__ b2, const float* __restrict__ g2, const float* __restrict__ be2,
    const float* __restrict__ b3, const float* __restrict__ g3, const float* __restrict__ be3,
    void* __restrict__ out, int N)
{
    __shared__ unsigned short s_x[TE * XS];
    __shared__ unsigned short s_y[TE * YS];
    __shared__ float s_red[TE * 4];
    __shared__ float s_ms[TE * 2];

    int t = threadIdx.x, nb = blockIdx.x * TE;

    for (int c = t; c < TE * 32; c += 256) {   // ax part
        int row = c >> 5, k4 = c & 31;
        int gr = nb + row;
        float4 v = make_float4(0, 0, 0, 0);
        if (gr < N) v = *(const float4*)(ax + (size_t)gr * 128 + k4 * 4);
        ushort4 o; o.x = f2h(v.x); o.y = f2h(v.y); o.z = f2h(v.z); o.w = f2h(v.w);
        *(ushort4*)(s_x + row * XS + k4 * 4) = o;
    }
    for (int c = t; c < TE * 32; c += 256) {   // agg part
        int row = c >> 5, k4 = c & 31;
        int gr = nb + row;
        float4 v = make_float4(0, 0, 0, 0);
        if (gr < N) v = *(const float4*)(agg + (size_t)gr * 128 + k4 * 4);
        ushort4 o; o.x = f2h(v.x); o.y = f2h(v.y); o.z = f2h(v.z); o.w = f2h(v.w);
        *(ushort4*)(s_x + row * XS + 128 + k4 * 4) = o;
    }
    __syncthreads();

    int l = t & 63, w = t >> 6;
    int n15 = l & 15, q = l >> 4;
    int rb = (w & 1) * 16, cb = (w >> 1) * 64, wcol = w >> 1;

    f32x4 acc[4];
    gemm_f16<8>(s_x, XS, Wp1, rb, cb, n15, q, acc);
    ln_relu(acc, b1, g1, be1, s_red, s_ms, rb, cb, n15, q, wcol, t);
#pragma unroll
    for (int ct = 0; ct < 4; ++ct)
#pragma unroll
        for (int r = 0; r < 4; ++r)
            s_y[(rb + q * 4 + r) * YS + cb + ct * 16 + n15] = f2h(acc[ct][r]);
    __syncthreads();
    gemm_f16<4>(s_y, YS, Wp2, rb, cb, n15, q, acc);
    ln_relu(acc, b2, g2, be2, s_red, s_ms, rb, cb, n15, q, wcol, t);
#pragma unroll
    for (int ct = 0; ct < 4; ++ct)    // f2 -> s_x cols 128..255 (th = [ax | f2])
#pragma unroll
        for (int r = 0; r < 4; ++r)
            s_x[(rb + q * 4 + r) * XS + 128 + cb + ct * 16 + n15] = f2h(acc[ct][r]);
    __syncthreads();
    gemm_f16<8>(s_x, XS, Wp3, rb, cb, n15, q, acc);
    ln_relu(acc, b3, g3, be3, s_red, s_ms, rb, cb, n15, q, wcol, t);

#pragma unroll
    for (int ct = 0; ct < 4; ++ct)
#pragma unroll
        for (int r = 0; r < 4; ++r) {
            int row = rb + q * 4 + r;
            int gr = nb + row;
            int col = cb + ct * 16 + n15;
            if (gr < N) {
                if (OUT_F16)
                    ((unsigned short*)out)[(size_t)gr * D + col] = f2h(acc[ct][r]);
                else
                    ((float*)out)[(size_t)gr * D + col] = acc[ct][r];
            }
        }
}

extern "C" void kernel_launch(void* const* d_in, const int* in_sizes, int n_in,
                              void* d_out, int out_size, void* d_ws, size_t ws_size,
                              hipStream_t stream)
{
    const float* h2   = (const float*)d_in[0];
    const float* ax1  = (const float*)d_in[1];
    const float* ax0  = (const float*)d_in[2];
    const float* bx2  = (const float*)d_in[3];
    const float* bx1  = (const float*)d_in[4];
    const float* brW1 = (const float*)d_in[5];
    const float* brb1 = (const float*)d_in[6];
    const float* brg1 = (const float*)d_in[7];
    const float* brbe1= (const float*)d_in[8];
    const float* brW2 = (const float*)d_in[9];
    const float* brb2 = (const float*)d_in[10];
    const float* brg2 = (const float*)d_in[11];
    const float* brbe2= (const float*)d_in[12];
    const float* sW1  = (const float*)d_in[13];
    const float* sb1  = (const float*)d_in[14];
    const float* sg1  = (const float*)d_in[15];
    const float* sbe1 = (const float*)d_in[16];
    const float* sW2  = (const float*)d_in[17];
    const float* sb2  = (const float*)d_in[18];
    const float* sg2  = (const float*)d_in[19];
    const float* sbe2 = (const float*)d_in[20];
    const float* hW   = (const float*)d_in[21];
    const float* hb   = (const float*)d_in[22];
    const float* hg   = (const float*)d_in[23];
    const float* hbe  = (const float*)d_in[24];
    const int*   src2 = (const int*)d_in[25];
    const int*   dst2 = (const int*)d_in[26];
    const int*   src1 = (const int*)d_in[27];
    const int*   dst1 = (const int*)d_in[28];

    int n2 = in_sizes[0] / D;
    int n1 = in_sizes[1] / D;
    int n0 = in_sizes[2] / D;

    // workspace layout
    unsigned short* Wp  = (unsigned short*)d_ws;          // 262144 fp16 = 512 KB
    float*          agg = (float*)((char*)d_ws + 524288); // n1*128 fp32 (reused for n0)
    unsigned short* h1  = (unsigned short*)(agg + (size_t)n1 * D); // n1*128 fp16

    // packed-weight pointers (level stride)
    const unsigned short* pBr1[2] = { Wp + 0,      Wp + 32768 };
    const unsigned short* pBr2[2] = { Wp + 65536,  Wp + 65536  + 16384 };
    const unsigned short* pS1 [2] = { Wp + 98304,  Wp + 98304  + 32768 };
    const unsigned short* pS2 [2] = { Wp + 163840, Wp + 163840 + 16384 };
    const unsigned short* pH  [2] = { Wp + 196608, Wp + 196608 + 32768 };

    pack_w<<<dim3(1024), dim3(256), 0, stream>>>(brW1, brW2, sW1, sW2, hW, Wp);

    // ---- iteration 0 (level 2 -> 1) ----
    hipMemsetAsync(agg, 0, (size_t)n1 * D * sizeof(float), stream);
    edge_mlp<false><<<dim3((n2 + TE - 1) / TE), dim3(256), 0, stream>>>(
        h2, bx2, src2, dst2, pBr1[0], pBr2[0],
        brb1, brg1, brbe1, brb2, brg2, brbe2, agg, n2);
    node_mlp<true><<<dim3((n1 + TE - 1) / TE), dim3(256), 0, stream>>>(
        ax1, agg, pS1[0], pS2[0], pH[0],
        sb1, sg1, sbe1, sb2, sg2, sbe2, hb, hg, hbe, h1, n1);

    // ---- iteration 1 (level 1 -> 0) ----
    hipMemsetAsync(agg, 0, (size_t)n0 * D * sizeof(float), stream);
    edge_mlp<true><<<dim3((n1 + TE - 1) / TE), dim3(256), 0, stream>>>(
        h1, bx1, src1, dst1, pBr1[1], pBr2[1],
        brb1 + D, brg1 + D, brbe1 + D, brb2 + D, brg2 + D, brbe2 + D, agg, n1);
    node_mlp<false><<<dim3((n0 + TE - 1) / TE), dim3(256), 0, stream>>>(
        ax0, agg, pS1[1], pS2[1], pH[1],
        sb1 + D, sg1 + D, sbe1 + D, sb2 + D, sg2 + D, sbe2 + D,
        hb + D, hg + D, hbe + D, d_out, n0);
}